// Round 1
// baseline (1726.542 us; speedup 1.0000x reference)
//
#include <hip/hip_runtime.h>
#include <math.h>

#define HH 1024
#define WW 1024
#define CHN 3
#define PLANE (HH*WW)
#define IMG (CHN*PLANE)
#define NREG 5
#define EPSV 1e-4f

// ---- workspace layout (in floats) ----
// w_reg: 5*IMG | KtWb: IMG | t: IMG | r: IMG | p: IMG | Ap: IMG | partials | scalars
#define OFF_WREG 0
#define OFF_KTWB (5*IMG)
#define OFF_T    (6*IMG)
#define OFF_R    (7*IMG)
#define OFF_P    (8*IMG)
#define OFF_AP   (9*IMG)
#define OFF_PART (10*IMG)          // pAp[1024], rr[1024], then rr2[1024]
#define OFF_SCAL (10*IMG + 3072)   // [0]=alpha [1]=rr [2]=beta

// ---------------------------------------------------------------------------
// init: w_reg = 1, x = blurred
__global__ __launch_bounds__(256) void k_init(const float4* __restrict__ b,
                                              float4* __restrict__ x,
                                              float4* __restrict__ wreg) {
  const int stride = gridDim.x * 256;
  const float4 one = make_float4(1.f, 1.f, 1.f, 1.f);
  for (int i = blockIdx.x * 256 + threadIdx.x; i < NREG * IMG / 4; i += stride) {
    wreg[i] = one;
    if (i < IMG / 4) x[i] = b[i];
  }
}

// ---------------------------------------------------------------------------
// 15x15 edge-padded correlation. Tile: 64 cols x 128 rows out, LDS 142x78.
// 256 threads, each computes 4 rows x 8 cols.
template <bool FLIP>
__global__ __launch_bounds__(256) void k_corr15(const float* __restrict__ in,
                                                const float* __restrict__ k15,
                                                float* __restrict__ out) {
  __shared__ float tile[142 * 78];
  const int c = blockIdx.z;
  const int R0 = blockIdx.y * 128;
  const int C0 = blockIdx.x * 64;
  const float* inc = in + c * PLANE;
  for (int i = threadIdx.x; i < 142 * 78; i += 256) {
    int r = i / 78, col = i - r * 78;
    int gr = min(max(R0 - 7 + r, 0), HH - 1);
    int gc = min(max(C0 - 7 + col, 0), WW - 1);
    tile[i] = inc[gr * WW + gc];
  }
  __syncthreads();
  const int tx = threadIdx.x & 7;    // col group (8 cols each)
  const int ty = threadIdx.x >> 3;   // row group (4 rows each), 0..31
  const int oi = ty * 4, oj = tx * 8;
  float acc[4][8];
#pragma unroll
  for (int o = 0; o < 4; ++o)
#pragma unroll
    for (int q = 0; q < 8; ++q) acc[o][q] = 0.f;

#pragma unroll 1
  for (int rr = 0; rr < 18; ++rr) {  // input-row offset within window
    float wv[22];
#pragma unroll
    for (int q = 0; q < 22; ++q) wv[q] = tile[(oi + rr) * 78 + oj + q];
#pragma unroll
    for (int o = 0; o < 4; ++o) {
      int a = rr - o;
      if (a >= 0 && a < 15) {
#pragma unroll
        for (int b = 0; b < 15; ++b) {
          float kv = FLIP ? k15[(14 - a) * 15 + (14 - b)] : k15[a * 15 + b];
#pragma unroll
          for (int q = 0; q < 8; ++q) acc[o][q] = fmaf(kv, wv[b + q], acc[o][q]);
        }
      }
    }
  }
  float* oc = out + c * PLANE + (R0 + oi) * WW + C0 + oj;
#pragma unroll
  for (int o = 0; o < 4; ++o) {
    float4* dst = (float4*)(oc + o * WW);
    dst[0] = make_float4(acc[o][0], acc[o][1], acc[o][2], acc[o][3]);
    dst[1] = make_float4(acc[o][4], acc[o][5], acc[o][6], acc[o][7]);
  }
}

// ---------------------------------------------------------------------------
__device__ __forceinline__ void blk_reduce2(float a, float b, float* scratch,
                                            float* o1, float* o2) {
#pragma unroll
  for (int off = 32; off > 0; off >>= 1) {
    a += __shfl_down(a, off, 64);
    b += __shfl_down(b, off, 64);
  }
  __syncthreads();
  const int lane = threadIdx.x & 63, wid = threadIdx.x >> 6;
  if (lane == 0) { scratch[wid] = a; scratch[4 + wid] = b; }
  __syncthreads();
  if (threadIdx.x == 0) {
    *o1 = scratch[0] + scratch[1] + scratch[2] + scratch[3];
    *o2 = scratch[4] + scratch[5] + scratch[6] + scratch[7];
  }
}

// ---------------------------------------------------------------------------
// Fused reg-term (+corr15-of-t) kernel.
// MODE 0: out = corr15(t,flipK) + reg(src)        ; also partials pAp, rr
// MODE 1: out = corr15(t,flipK) + reg(src)        ; no partials
// MODE 2: out(r) = ktwb - apin + reg(src=blurred, inner=rtk); pout(p) = r
// reg(src) = sum_n lam_n * corr5( wreg_n .* corr5(src, inner_n), flip(rk_n) )
// Tile 64x64, 256 threads, 4x4 outputs each. All edge-pads via clamp.
template <int MODE>
__global__ __launch_bounds__(256) void k_reg(
    const float* __restrict__ src, const float* __restrict__ tin,
    const float* __restrict__ k15, const float* __restrict__ rk,
    const float* __restrict__ kin_all, const float* __restrict__ rkw,
    const float* __restrict__ wreg, const float* __restrict__ ktwb,
    const float* __restrict__ apin, const float* __restrict__ rin,
    float* __restrict__ out, float* __restrict__ pout,
    float* __restrict__ part) {
  __shared__ float sbuf[78 * 78];   // src tile (72x72 @ stride 78), later t (78x78)
  __shared__ float vbuf[68 * 68];   // weighted inner-corr tile
  const int c = blockIdx.z;
  const int R0 = blockIdx.y * 64, C0 = blockIdx.x * 64;
  const int tid = threadIdx.x;

  const float* sc = src + c * PLANE;
  for (int i = tid; i < 72 * 72; i += 256) {
    int r = i / 72, col = i - r * 72;
    int gr = min(max(R0 - 4 + r, 0), HH - 1);
    int gc = min(max(C0 - 4 + col, 0), WW - 1);
    sbuf[r * 78 + col] = sc[gr * WW + gc];
  }
  __syncthreads();

  const int tx = tid & 15, ty = tid >> 4;
  const int oi = ty * 4, oj = tx * 4;
  float acc[4][4];
#pragma unroll
  for (int o = 0; o < 4; ++o)
#pragma unroll
    for (int q = 0; q < 4; ++q) acc[o][q] = 0.f;

#pragma unroll 1
  for (int n = 0; n < NREG; ++n) {
    float lw = rkw[n];
    const float lam = lw * lw;
    const float* kin = kin_all + n * 25;
    const float* kout = rk + n * 25;
    const float* wr = wreg + (n * CHN + c) * PLANE;
    // build v = wreg .* corr5(src, kin) on the (tile+2)-halo, clamped
    for (int e = tid; e < 68 * 68; e += 256) {
      int vr = e / 68, vc = e - vr * 68;
      int cgr = min(max(R0 - 2 + vr, 0), HH - 1);
      int cgc = min(max(C0 - 2 + vc, 0), WW - 1);
      int sr = cgr - R0 + 2;   // sbuf row for tap a=0
      int scl = cgc - C0 + 2;  // sbuf col for tap b=0
      float s = 0.f;
#pragma unroll
      for (int a = 0; a < 5; ++a)
#pragma unroll
        for (int b = 0; b < 5; ++b)
          s = fmaf(kin[a * 5 + b], sbuf[(sr + a) * 78 + scl + b], s);
      vbuf[e] = s * wr[cgr * WW + cgc];
    }
    __syncthreads();
    // accumulate lam * corr5(v, flip(kout)) on the 4x4 outputs
#pragma unroll 1
    for (int ra = 0; ra < 8; ++ra) {
      float vw[8];
#pragma unroll
      for (int q = 0; q < 8; ++q) vw[q] = vbuf[(oi + ra) * 68 + oj + q];
#pragma unroll
      for (int o = 0; o < 4; ++o) {
        int a = ra - o;
        if (a >= 0 && a < 5) {
#pragma unroll
          for (int b = 0; b < 5; ++b) {
            float kv = lam * kout[(4 - a) * 5 + (4 - b)];
#pragma unroll
            for (int q = 0; q < 4; ++q) acc[o][q] = fmaf(kv, vw[b + q], acc[o][q]);
          }
        }
      }
    }
    __syncthreads();
  }

  if constexpr (MODE != 2) {
    // overwrite sbuf with t tile (78x78, pad 7) and add corr15(t, flipK)
    const float* tc = tin + c * PLANE;
    for (int i = tid; i < 78 * 78; i += 256) {
      int r = i / 78, col = i - r * 78;
      int gr = min(max(R0 - 7 + r, 0), HH - 1);
      int gc = min(max(C0 - 7 + col, 0), WW - 1);
      sbuf[i] = tc[gr * WW + gc];
    }
    __syncthreads();
#pragma unroll 1
    for (int rr = 0; rr < 18; ++rr) {
      float wv[19];
#pragma unroll
      for (int q = 0; q < 19; ++q) wv[q] = sbuf[(oi + rr) * 78 + oj + q];
#pragma unroll
      for (int o = 0; o < 4; ++o) {
        int a = rr - o;
        if (a >= 0 && a < 15) {
#pragma unroll
          for (int b = 0; b < 15; ++b) {
            float kv = k15[(14 - a) * 15 + (14 - b)];
#pragma unroll
            for (int q = 0; q < 4; ++q) acc[o][q] = fmaf(kv, wv[b + q], acc[o][q]);
          }
        }
      }
    }
  }

  const int obase = c * PLANE + (R0 + oi) * WW + C0 + oj;
  if constexpr (MODE != 2) {
#pragma unroll
    for (int o = 0; o < 4; ++o)
      *(float4*)(out + obase + o * WW) =
          make_float4(acc[o][0], acc[o][1], acc[o][2], acc[o][3]);
    if constexpr (MODE == 0) {
      float pap = 0.f, rr2 = 0.f;
#pragma unroll
      for (int o = 0; o < 4; ++o) {
        float4 pv = *(const float4*)(src + obase + o * WW);
        float4 rv = *(const float4*)(rin + obase + o * WW);
        pap += acc[o][0] * pv.x + acc[o][1] * pv.y + acc[o][2] * pv.z + acc[o][3] * pv.w;
        rr2 += rv.x * rv.x + rv.y * rv.y + rv.z * rv.z + rv.w * rv.w;
      }
      float s1, s2;
      blk_reduce2(pap, rr2, vbuf, &s1, &s2);
      if (tid == 0) {
        int bid = (blockIdx.z * 16 + blockIdx.y) * 16 + blockIdx.x;
        part[bid] = s1;
        part[1024 + bid] = s2;
      }
    }
  } else {
#pragma unroll
    for (int o = 0; o < 4; ++o) {
      float4 kw = *(const float4*)(ktwb + obase + o * WW);
      float4 ap = *(const float4*)(apin + obase + o * WW);
      float4 rv = make_float4(kw.x - ap.x + acc[o][0], kw.y - ap.y + acc[o][1],
                              kw.z - ap.z + acc[o][2], kw.w - ap.w + acc[o][3]);
      *(float4*)(out + obase + o * WW) = rv;
      *(float4*)(pout + obase + o * WW) = rv;
    }
  }
}

// ---------------------------------------------------------------------------
// w_reg update: d_n = corr5(x,rk_n) - corr5(blurred,rtk_n);
// w_n = pw_n * (|d|+eps)^(pw_n-2)
__global__ __launch_bounds__(256) void k_wupd(
    const float* __restrict__ x, const float* __restrict__ blur,
    const float* __restrict__ rk, const float* __restrict__ rtk,
    const float* __restrict__ rp, float* __restrict__ wreg) {
  __shared__ float xb[68 * 68];
  __shared__ float bb[68 * 68];
  const int c = blockIdx.z, R0 = blockIdx.y * 64, C0 = blockIdx.x * 64;
  const int tid = threadIdx.x;
  const float* xc = x + c * PLANE;
  const float* bc = blur + c * PLANE;
  for (int i = tid; i < 68 * 68; i += 256) {
    int r = i / 68, col = i - r * 68;
    int gr = min(max(R0 - 2 + r, 0), HH - 1);
    int gc = min(max(C0 - 2 + col, 0), WW - 1);
    xb[i] = xc[gr * WW + gc];
    bb[i] = bc[gr * WW + gc];
  }
  __syncthreads();
  const int tx = tid & 15, ty = tid >> 4;
  const int oi = ty * 4, oj = tx * 4;
#pragma unroll 1
  for (int n = 0; n < NREG; ++n) {
    const float* k1 = rk + n * 25;
    const float* k2 = rtk + n * 25;
    float pw = rp[n];
    float* wc = wreg + (n * CHN + c) * PLANE + (R0 + oi) * WW + C0 + oj;
#pragma unroll
    for (int o = 0; o < 4; ++o) {
      float tmp[4];
#pragma unroll
      for (int q = 0; q < 4; ++q) {
        float d = 0.f;
#pragma unroll
        for (int a = 0; a < 5; ++a)
#pragma unroll
          for (int b = 0; b < 5; ++b) {
            int idx = (oi + o + a) * 68 + oj + q + b;
            d += k1[a * 5 + b] * xb[idx] - k2[a * 5 + b] * bb[idx];
          }
        tmp[q] = pw * powf(fabsf(d) + EPSV, pw - 2.0f);
      }
      *(float4*)(wc + o * WW) = make_float4(tmp[0], tmp[1], tmp[2], tmp[3]);
    }
  }
}

// ---------------------------------------------------------------------------
// CG scalar/update kernels (scalars live in ws; no host sync)
__global__ __launch_bounds__(256) void k_sumfin1(const float* __restrict__ part,
                                                 float* __restrict__ scal) {
  __shared__ float scratch[8];
  float a = 0.f, b = 0.f;
  for (int i = threadIdx.x; i < 768; i += 256) {
    a += part[i];          // sum p.Ap
    b += part[1024 + i];   // sum r.r
  }
  float s1, s2;
  blk_reduce2(a, b, scratch, &s1, &s2);
  if (threadIdx.x == 0) {
    scal[0] = s2 / s1;  // alpha = rr / pAp
    scal[1] = s2;       // rr
  }
}

__global__ __launch_bounds__(256) void k_upd_xr(
    float4* __restrict__ x, const float4* __restrict__ p,
    float4* __restrict__ r, const float4* __restrict__ ap,
    const float* __restrict__ scal, float* __restrict__ part2) {
  __shared__ float scratch[8];
  const float alpha = scal[0];
  float s = 0.f;
  const int stride = gridDim.x * 256;
  for (int i = blockIdx.x * 256 + threadIdx.x; i < IMG / 4; i += stride) {
    float4 xv = x[i], pv = p[i], rv = r[i], av = ap[i];
    xv.x += alpha * pv.x; xv.y += alpha * pv.y; xv.z += alpha * pv.z; xv.w += alpha * pv.w;
    rv.x -= alpha * av.x; rv.y -= alpha * av.y; rv.z -= alpha * av.z; rv.w -= alpha * av.w;
    x[i] = xv; r[i] = rv;
    s += rv.x * rv.x + rv.y * rv.y + rv.z * rv.z + rv.w * rv.w;
  }
#pragma unroll
  for (int off = 32; off > 0; off >>= 1) s += __shfl_down(s, off, 64);
  if ((threadIdx.x & 63) == 0) scratch[threadIdx.x >> 6] = s;
  __syncthreads();
  if (threadIdx.x == 0)
    part2[blockIdx.x] = scratch[0] + scratch[1] + scratch[2] + scratch[3];
}

__global__ __launch_bounds__(256) void k_upd_x(
    float4* __restrict__ x, const float4* __restrict__ p,
    const float* __restrict__ scal) {
  const float alpha = scal[0];
  const int stride = gridDim.x * 256;
  for (int i = blockIdx.x * 256 + threadIdx.x; i < IMG / 4; i += stride) {
    float4 xv = x[i], pv = p[i];
    xv.x += alpha * pv.x; xv.y += alpha * pv.y; xv.z += alpha * pv.z; xv.w += alpha * pv.w;
    x[i] = xv;
  }
}

__global__ __launch_bounds__(256) void k_sumfin2(const float* __restrict__ part2,
                                                 float* __restrict__ scal) {
  __shared__ float scratch[8];
  float a = 0.f;
  for (int i = threadIdx.x; i < 768; i += 256) a += part2[i];
  float s1, s2;
  blk_reduce2(a, 0.f, scratch, &s1, &s2);
  if (threadIdx.x == 0) scal[2] = s1 / scal[1];  // beta = rr_new / rr
}

__global__ __launch_bounds__(256) void k_upd_p(
    float4* __restrict__ p, const float4* __restrict__ r,
    const float* __restrict__ scal) {
  const float beta = scal[2];
  const int stride = gridDim.x * 256;
  for (int i = blockIdx.x * 256 + threadIdx.x; i < IMG / 4; i += stride) {
    float4 pv = p[i], rv = r[i];
    pv.x = rv.x + beta * pv.x; pv.y = rv.y + beta * pv.y;
    pv.z = rv.z + beta * pv.z; pv.w = rv.w + beta * pv.w;
    p[i] = pv;
  }
}

// ---------------------------------------------------------------------------
extern "C" void kernel_launch(void* const* d_in, const int* in_sizes, int n_in,
                              void* d_out, int out_size, void* d_ws, size_t ws_size,
                              hipStream_t stream) {
  (void)in_sizes; (void)n_in; (void)out_size; (void)ws_size;
  const float* blurred = (const float*)d_in[0];
  const float* k15 = (const float*)d_in[1];
  const float* rk  = (const float*)d_in[2];
  const float* rkw = (const float*)d_in[3];
  const float* rtk = (const float*)d_in[4];
  const float* rp  = (const float*)d_in[5];
  // d_in[6]=num_irls_iter(2), d_in[7]=num_cg_iter(4): fixed for this instance

  float* x = (float*)d_out;
  float* ws = (float*)d_ws;
  float* wreg  = ws + OFF_WREG;
  float* ktwb  = ws + OFF_KTWB;
  float* t     = ws + OFF_T;
  float* r     = ws + OFF_R;
  float* p     = ws + OFF_P;
  float* ap    = ws + OFF_AP;
  float* part  = ws + OFF_PART;
  float* part2 = part + 2048;
  float* scal  = ws + OFF_SCAL;

  const dim3 b256(256);
  const dim3 g15(16, 8, CHN);    // corr15 tiles: 64x128
  const dim3 g64(16, 16, CHN);   // 64x64 tiles

  k_init<<<dim3(2048), b256, 0, stream>>>((const float4*)blurred, (float4*)x,
                                          (float4*)wreg);
  k_corr15<true><<<g15, b256, 0, stream>>>(blurred, k15, ktwb);

  for (int irls = 0; irls < 2; ++irls) {
    // r = rhs - A(x0);  p = r
    k_corr15<false><<<g15, b256, 0, stream>>>(x, k15, t);
    k_reg<1><<<g64, b256, 0, stream>>>(x, t, k15, rk, rk, rkw, wreg,
                                       nullptr, nullptr, nullptr, ap, nullptr, nullptr);
    k_reg<2><<<g64, b256, 0, stream>>>(blurred, nullptr, k15, rk, rtk, rkw, wreg,
                                       ktwb, ap, nullptr, r, p, nullptr);
    for (int cg = 0; cg < 4; ++cg) {
      const bool last = (cg == 3);
      k_corr15<false><<<g15, b256, 0, stream>>>(p, k15, t);
      k_reg<0><<<g64, b256, 0, stream>>>(p, t, k15, rk, rk, rkw, wreg,
                                         nullptr, nullptr, r, ap, nullptr, part);
      k_sumfin1<<<dim3(1), b256, 0, stream>>>(part, scal);
      if (!last) {
        k_upd_xr<<<dim3(768), b256, 0, stream>>>((float4*)x, (const float4*)p,
                                                 (float4*)r, (const float4*)ap,
                                                 scal, part2);
        k_sumfin2<<<dim3(1), b256, 0, stream>>>(part2, scal);
        k_upd_p<<<dim3(768), b256, 0, stream>>>((float4*)p, (const float4*)r, scal);
      } else {
        k_upd_x<<<dim3(768), b256, 0, stream>>>((float4*)x, (const float4*)p, scal);
      }
    }
    if (irls == 0)
      k_wupd<<<g64, b256, 0, stream>>>(x, blurred, rk, rtk, rp, wreg);
  }
}

// Round 4
// 1653.966 us; speedup vs baseline: 1.0439x; 1.0439x over previous
//
#include <hip/hip_runtime.h>
#include <math.h>

#define HH 1024
#define WW 1024
#define CHN 3
#define PLANE (HH*WW)
#define IMG (CHN*PLANE)
#define NREG 5
#define EPSV 1e-4f

// ---- workspace layout (in floats) ----
#define OFF_WREG 0
#define OFF_KTWB (5*IMG)
#define OFF_T    (6*IMG)
#define OFF_R    (7*IMG)
#define OFF_P    (8*IMG)
#define OFF_AP   (9*IMG)
#define OFF_PART (10*IMG)          // pAp[1024] | rr[1024] | rr_new[1024]

// ---------------------------------------------------------------------------
__global__ __launch_bounds__(256) void k_init(const float4* __restrict__ b,
                                              float4* __restrict__ x,
                                              float4* __restrict__ wreg) {
  const int stride = gridDim.x * 256;
  const float4 one = make_float4(1.f, 1.f, 1.f, 1.f);
  for (int i = blockIdx.x * 256 + threadIdx.x; i < NREG * IMG / 4; i += stride) {
    wreg[i] = one;
    if (i < IMG / 4) x[i] = b[i];
  }
}

// ---------------------------------------------------------------------------
// 15x15 edge-padded correlation. Tile 72 cols x 64 rows, 128 threads.
// Col-group stride 9 (9 cols/thread) -> LDS bank spread <=2-way (free).
// k15 staged (optionally flipped) into LDS padded 16/row; read via b128 bcast.
template <bool FLIP>
__global__ __launch_bounds__(128) void k_corr15(const float* __restrict__ in,
                                                const float* __restrict__ k15,
                                                float* __restrict__ out) {
  __shared__ float tile[78 * 87];
  __shared__ float kpad[15 * 16];
  const int ch = blockIdx.z;
  const int R0 = blockIdx.y * 64;
  const int C0 = blockIdx.x * 72;
  const int tid = threadIdx.x;
  for (int i = tid; i < 240; i += 128) {
    int a = i >> 4, b = i & 15;
    float v = 0.f;
    if (b < 15) v = FLIP ? k15[(14 - a) * 15 + (14 - b)] : k15[a * 15 + b];
    kpad[i] = v;
  }
  const float* inc = in + ch * PLANE;
  for (int i = tid; i < 78 * 86; i += 128) {
    int r = i / 86, c = i - r * 86;
    int gr = min(max(R0 - 7 + r, 0), HH - 1);
    int gc = min(max(C0 - 7 + c, 0), WW - 1);
    tile[r * 87 + c] = inc[gr * WW + gc];
  }
  __syncthreads();
  const int tx = tid & 7, ty = tid >> 3;  // 8 col-groups x 16 row-groups
  const int oi = ty * 4, oj = tx * 9;
  float acc[4][9];
#pragma unroll
  for (int o = 0; o < 4; ++o)
#pragma unroll
    for (int q = 0; q < 9; ++q) acc[o][q] = 0.f;

#pragma unroll 1
  for (int rr = 0; rr < 18; ++rr) {
    float wv[23];
#pragma unroll
    for (int q = 0; q < 23; ++q) wv[q] = tile[(oi + rr) * 87 + oj + q];
#pragma unroll
    for (int o = 0; o < 4; ++o) {
      int a = rr - o;
      if ((unsigned)a < 15u) {
        const float4* kp = (const float4*)&kpad[a * 16];
        float4 kA = kp[0], kB = kp[1], kC = kp[2], kD = kp[3];
        float kv[16] = {kA.x, kA.y, kA.z, kA.w, kB.x, kB.y, kB.z, kB.w,
                        kC.x, kC.y, kC.z, kC.w, kD.x, kD.y, kD.z, kD.w};
#pragma unroll
        for (int b = 0; b < 15; ++b)
#pragma unroll
          for (int q = 0; q < 9; ++q)
            acc[o][q] = fmaf(kv[b], wv[b + q], acc[o][q]);
      }
    }
  }
  float* oc = out + ch * PLANE;
#pragma unroll
  for (int o = 0; o < 4; ++o) {
    const int orow = R0 + oi + o;
#pragma unroll
    for (int q = 0; q < 9; ++q) {
      int gcol = C0 + oj + q;
      if (gcol < WW) oc[orow * WW + gcol] = acc[o][q];
    }
  }
}

// ---------------------------------------------------------------------------
__device__ __forceinline__ void blk_reduce2(float a, float b, float* scratch,
                                            float* o1, float* o2) {
#pragma unroll
  for (int off = 32; off > 0; off >>= 1) {
    a += __shfl_down(a, off, 64);
    b += __shfl_down(b, off, 64);
  }
  __syncthreads();
  const int lane = threadIdx.x & 63, wid = threadIdx.x >> 6;
  if (lane == 0) { scratch[wid] = a; scratch[4 + wid] = b; }
  __syncthreads();
  if (threadIdx.x == 0) {
    *o1 = scratch[0] + scratch[1] + scratch[2] + scratch[3];
    *o2 = scratch[4] + scratch[5] + scratch[6] + scratch[7];
  }
}

// ---------------------------------------------------------------------------
// Pure reg-term kernel: acc = sum_n lam_n * corr5(w_n .* corr5(src,kin_n), flip(rk_n))
// MODE 0: ap += acc (ap holds corr15(corr15(p))); partials pAp, rr
// MODE 1: ap += acc
// MODE 2: r = ktwb - ap + acc; p = r   (src=blurred, kin=rtk)
// Col-per-lane sliding windows, 5x5 kernels in VGPRs, conflict-free LDS.
template <int MODE>
__global__ __launch_bounds__(256) void k_reg(
    const float* __restrict__ src, const float* __restrict__ kin_all,
    const float* __restrict__ rk, const float* __restrict__ rkw,
    const float* __restrict__ wreg, const float* __restrict__ ktwb,
    float* __restrict__ ap, const float* __restrict__ rin,
    float* __restrict__ rout, float* __restrict__ pout,
    float* __restrict__ part) {
  __shared__ float sbuf[72 * 73];
  __shared__ float vbuf[68 * 69];
  __shared__ float kin_s[NREG * 25];
  __shared__ float kf_s[NREG * 25];
  __shared__ float scratch[8];
  const int ch = blockIdx.z;
  const int R0 = blockIdx.y * 64, C0 = blockIdx.x * 64;
  const int tid = threadIdx.x;
  const int lane = tid & 63, wid = tid >> 6;
  const int W = wid * 16;

  if (tid < NREG * 25) {
    int n = tid / 25, j = tid - n * 25, a = j / 5, b = j - a * 5;
    kin_s[tid] = kin_all[tid];
    float lw = rkw[n];
    kf_s[tid] = lw * lw * rk[n * 25 + (4 - a) * 5 + (4 - b)];
  }
  const float* sc = src + ch * PLANE;
  for (int i = tid; i < 72 * 72; i += 256) {
    int r = i / 72, c = i - r * 72;
    int gr = min(max(R0 - 4 + r, 0), HH - 1);
    int gc = min(max(C0 - 4 + c, 0), WW - 1);
    sbuf[r * 73 + c] = sc[gr * WW + gc];
  }
  __syncthreads();

  float acc[16];
#pragma unroll
  for (int s = 0; s < 16; ++s) acc[s] = 0.f;

  for (int n = 0; n < NREG; ++n) {
    float kin[25];
#pragma unroll
    for (int j = 0; j < 25; ++j) kin[j] = kin_s[n * 25 + j];
    const float* wn = wreg + (n * CHN + ch) * PLANE;

    // border ring of v (center-clamped evaluation = edge replication of inner result)
    for (int e = tid; e < 528; e += 256) {
      int vr, vc;
      if (e < 136)      { vr = e / 68;                 vc = e - (e / 68) * 68; }
      else if (e < 272) { int j2 = e - 136; vr = 66 + j2 / 68; vc = j2 - (j2 / 68) * 68; }
      else if (e < 400) { int j2 = e - 272; vr = 2 + (j2 >> 1); vc = j2 & 1; }
      else              { int j2 = e - 400; vr = 2 + (j2 >> 1); vc = 66 + (j2 & 1); }
      int rc = min(max(R0 - 2 + vr, 0), HH - 1);
      int cc = min(max(C0 - 2 + vc, 0), WW - 1);
      int tr = rc - R0 + 2, tc = cc - C0 + 2;
      float s = 0.f;
#pragma unroll
      for (int a = 0; a < 5; ++a)
#pragma unroll
        for (int b = 0; b < 5; ++b)
          s = fmaf(kin[a * 5 + b], sbuf[(tr + a) * 73 + tc + b], s);
      vbuf[vr * 69 + vc] = s * wn[rc * WW + cc];
    }

    // main 64x64 v region: col-per-lane vertical sliding, fully unrolled
    float vacc[16];
#pragma unroll
    for (int s = 0; s < 16; ++s) vacc[s] = 0.f;
#pragma unroll
    for (int rr = 0; rr < 20; ++rr) {
      float x5[5];
#pragma unroll
      for (int b = 0; b < 5; ++b) x5[b] = sbuf[(W + 2 + rr) * 73 + lane + 2 + b];
#pragma unroll
      for (int a = 0; a < 5; ++a) {
        int s = rr - a;
        if (s >= 0 && s < 16) {
#pragma unroll
          for (int b = 0; b < 5; ++b) vacc[s] = fmaf(kin[a * 5 + b], x5[b], vacc[s]);
        }
      }
    }
#pragma unroll
    for (int s = 0; s < 16; ++s)
      vbuf[(2 + W + s) * 69 + lane + 2] = vacc[s] * wn[(R0 + W + s) * WW + C0 + lane];
    __syncthreads();

    float kf[25];
#pragma unroll
    for (int j = 0; j < 25; ++j) kf[j] = kf_s[n * 25 + j];
#pragma unroll
    for (int rv = 0; rv < 20; ++rv) {
      float v5[5];
#pragma unroll
      for (int b = 0; b < 5; ++b) v5[b] = vbuf[(W + rv) * 69 + lane + b];
#pragma unroll
      for (int a = 0; a < 5; ++a) {
        int s = rv - a;
        if (s >= 0 && s < 16) {
#pragma unroll
          for (int b = 0; b < 5; ++b) acc[s] = fmaf(kf[a * 5 + b], v5[b], acc[s]);
        }
      }
    }
    __syncthreads();
  }

  const int obase = ch * PLANE + (R0 + W) * WW + C0 + lane;
  if constexpr (MODE == 2) {
#pragma unroll
    for (int s = 0; s < 16; ++s) {
      float rv = ktwb[obase + s * WW] - ap[obase + s * WW] + acc[s];
      rout[obase + s * WW] = rv;
      pout[obase + s * WW] = rv;
    }
  } else {
    float pap = 0.f, rr2 = 0.f;
#pragma unroll
    for (int s = 0; s < 16; ++s) {
      float av = ap[obase + s * WW] + acc[s];
      ap[obase + s * WW] = av;
      if constexpr (MODE == 0) {
        float pv = src[obase + s * WW];
        float rv = rin[obase + s * WW];
        pap = fmaf(av, pv, pap);
        rr2 = fmaf(rv, rv, rr2);
      }
    }
    if constexpr (MODE == 0) {
      float s1, s2;
      blk_reduce2(pap, rr2, scratch, &s1, &s2);
      if (tid == 0) {
        int bid = (blockIdx.z * 16 + blockIdx.y) * 16 + blockIdx.x;
        part[bid] = s1;
        part[1024 + bid] = s2;
      }
    }
  }
}

// ---------------------------------------------------------------------------
// w_reg update: d_n = corr5(x,rk_n) - corr5(blurred,rtk_n);
// w = pw * (|d|+eps)^(pw-2) via native v_log/v_exp. Col-per-lane, conflict-free.
__global__ __launch_bounds__(256) void k_wupd(
    const float* __restrict__ x, const float* __restrict__ blur,
    const float* __restrict__ rk, const float* __restrict__ rtk,
    const float* __restrict__ rp, float* __restrict__ wreg) {
  __shared__ float xb[68 * 69];
  __shared__ float bb[68 * 69];
  __shared__ float k1s[NREG * 25], k2s[NREG * 25];
  __shared__ float rps[NREG];
  const int ch = blockIdx.z, R0 = blockIdx.y * 64, C0 = blockIdx.x * 64;
  const int tid = threadIdx.x;
  const int lane = tid & 63, wid = tid >> 6, W = wid * 16;
  if (tid < NREG * 25) { k1s[tid] = rk[tid]; k2s[tid] = rtk[tid]; }
  if (tid < NREG) rps[tid] = rp[tid];
  const float* xc = x + ch * PLANE;
  const float* bc = blur + ch * PLANE;
  for (int i = tid; i < 68 * 68; i += 256) {
    int r = i / 68, c = i - r * 68;
    int gr = min(max(R0 - 2 + r, 0), HH - 1);
    int gc = min(max(C0 - 2 + c, 0), WW - 1);
    xb[r * 69 + c] = xc[gr * WW + gc];
    bb[r * 69 + c] = bc[gr * WW + gc];
  }
  __syncthreads();
  for (int n = 0; n < NREG; ++n) {
    float k1[25], k2[25];
#pragma unroll
    for (int j = 0; j < 25; ++j) { k1[j] = k1s[n * 25 + j]; k2[j] = k2s[n * 25 + j]; }
    float d_[16];
#pragma unroll
    for (int s = 0; s < 16; ++s) d_[s] = 0.f;
#pragma unroll
    for (int rr = 0; rr < 20; ++rr) {
      float x5[5], b5[5];
#pragma unroll
      for (int b = 0; b < 5; ++b) {
        x5[b] = xb[(W + rr) * 69 + lane + b];
        b5[b] = bb[(W + rr) * 69 + lane + b];
      }
#pragma unroll
      for (int a = 0; a < 5; ++a) {
        int s = rr - a;
        if (s >= 0 && s < 16) {
#pragma unroll
          for (int b = 0; b < 5; ++b) {
            d_[s] = fmaf(k1[a * 5 + b], x5[b], d_[s]);
            d_[s] = fmaf(-k2[a * 5 + b], b5[b], d_[s]);
          }
        }
      }
    }
    float pw = rps[n];
    float* wc = wreg + (n * CHN + ch) * PLANE + (R0 + W) * WW + C0 + lane;
#pragma unroll
    for (int s = 0; s < 16; ++s) {
      float v = fabsf(d_[s]) + EPSV;
      wc[s * WW] = pw * __expf((pw - 2.f) * __logf(v));
    }
  }
}

// ---------------------------------------------------------------------------
// CG update kernels; each derives its scalar from the partial arrays itself
// (768 L2-hot loads/iteration per block — cheaper than extra 1-block launches).
__global__ __launch_bounds__(256) void k_upd_xr(
    float4* __restrict__ x, const float4* __restrict__ p,
    float4* __restrict__ r, const float4* __restrict__ ap,
    const float* __restrict__ part, float* __restrict__ part2) {
  __shared__ float scratch[8];
  __shared__ float sAlpha;
  {
    float a = 0.f, b = 0.f;
    for (int i = threadIdx.x; i < 768; i += 256) {
      a += part[i];           // sum p.Ap
      b += part[1024 + i];    // sum r.r
    }
    float s1, s2;
    blk_reduce2(a, b, scratch, &s1, &s2);
    if (threadIdx.x == 0) sAlpha = s2 / s1;
    __syncthreads();
  }
  const float alpha = sAlpha;
  float s = 0.f;
  const int stride = gridDim.x * 256;
  for (int i = blockIdx.x * 256 + threadIdx.x; i < IMG / 4; i += stride) {
    float4 xv = x[i], pv = p[i], rv = r[i], av = ap[i];
    xv.x += alpha * pv.x; xv.y += alpha * pv.y; xv.z += alpha * pv.z; xv.w += alpha * pv.w;
    rv.x -= alpha * av.x; rv.y -= alpha * av.y; rv.z -= alpha * av.z; rv.w -= alpha * av.w;
    x[i] = xv; r[i] = rv;
    s += rv.x * rv.x + rv.y * rv.y + rv.z * rv.z + rv.w * rv.w;
  }
#pragma unroll
  for (int off = 32; off > 0; off >>= 1) s += __shfl_down(s, off, 64);
  __syncthreads();
  if ((threadIdx.x & 63) == 0) scratch[threadIdx.x >> 6] = s;
  __syncthreads();
  if (threadIdx.x == 0)
    part2[blockIdx.x] = scratch[0] + scratch[1] + scratch[2] + scratch[3];
}

__global__ __launch_bounds__(256) void k_upd_x(
    float4* __restrict__ x, const float4* __restrict__ p,
    const float* __restrict__ part) {
  __shared__ float scratch[8];
  __shared__ float sAlpha;
  {
    float a = 0.f, b = 0.f;
    for (int i = threadIdx.x; i < 768; i += 256) {
      a += part[i];
      b += part[1024 + i];
    }
    float s1, s2;
    blk_reduce2(a, b, scratch, &s1, &s2);
    if (threadIdx.x == 0) sAlpha = s2 / s1;
    __syncthreads();
  }
  const float alpha = sAlpha;
  const int stride = gridDim.x * 256;
  for (int i = blockIdx.x * 256 + threadIdx.x; i < IMG / 4; i += stride) {
    float4 xv = x[i], pv = p[i];
    xv.x += alpha * pv.x; xv.y += alpha * pv.y; xv.z += alpha * pv.z; xv.w += alpha * pv.w;
    x[i] = xv;
  }
}

__global__ __launch_bounds__(256) void k_upd_p(
    float4* __restrict__ p, const float4* __restrict__ r,
    const float* __restrict__ part, const float* __restrict__ part2) {
  __shared__ float scratch[8];
  __shared__ float sBeta;
  {
    float a = 0.f, b = 0.f;
    for (int i = threadIdx.x; i < 768; i += 256) {
      a += part2[i];          // rr_new
      b += part[1024 + i];    // rr_old
    }
    float s1, s2;
    blk_reduce2(a, b, scratch, &s1, &s2);
    if (threadIdx.x == 0) sBeta = s1 / s2;
    __syncthreads();
  }
  const float beta = sBeta;
  const int stride = gridDim.x * 256;
  for (int i = blockIdx.x * 256 + threadIdx.x; i < IMG / 4; i += stride) {
    float4 pv = p[i], rv = r[i];
    pv.x = rv.x + beta * pv.x; pv.y = rv.y + beta * pv.y;
    pv.z = rv.z + beta * pv.z; pv.w = rv.w + beta * pv.w;
    p[i] = pv;
  }
}

// ---------------------------------------------------------------------------
extern "C" void kernel_launch(void* const* d_in, const int* in_sizes, int n_in,
                              void* d_out, int out_size, void* d_ws, size_t ws_size,
                              hipStream_t stream) {
  (void)in_sizes; (void)n_in; (void)out_size; (void)ws_size;
  const float* blurred = (const float*)d_in[0];
  const float* k15 = (const float*)d_in[1];
  const float* rk  = (const float*)d_in[2];
  const float* rkw = (const float*)d_in[3];
  const float* rtk = (const float*)d_in[4];
  const float* rp  = (const float*)d_in[5];

  float* x = (float*)d_out;
  float* ws = (float*)d_ws;
  float* wreg  = ws + OFF_WREG;
  float* ktwb  = ws + OFF_KTWB;
  float* t     = ws + OFF_T;
  float* r     = ws + OFF_R;
  float* p     = ws + OFF_P;
  float* ap    = ws + OFF_AP;
  float* part  = ws + OFF_PART;
  float* part2 = part + 2048;

  const dim3 b256(256), b128(128);
  const dim3 g15(15, 16, CHN);   // corr15 tiles: 72x64
  const dim3 g64(16, 16, CHN);   // 64x64 tiles

  k_init<<<dim3(2048), b256, 0, stream>>>((const float4*)blurred, (float4*)x,
                                          (float4*)wreg);
  k_corr15<true><<<g15, b128, 0, stream>>>(blurred, k15, ktwb);

  for (int irls = 0; irls < 2; ++irls) {
    // ap = A(x0) = corr15(corr15(x,K),flipK) + reg(x0); then r = rhs - ap; p = r
    k_corr15<false><<<g15, b128, 0, stream>>>(x, k15, t);
    k_corr15<true><<<g15, b128, 0, stream>>>(t, k15, ap);
    k_reg<1><<<g64, b256, 0, stream>>>(x, rk, rk, rkw, wreg, nullptr, ap,
                                       nullptr, nullptr, nullptr, nullptr);
    k_reg<2><<<g64, b256, 0, stream>>>(blurred, rtk, rk, rkw, wreg, ktwb, ap,
                                       nullptr, r, p, nullptr);
    for (int cg = 0; cg < 4; ++cg) {
      const bool last = (cg == 3);
      k_corr15<false><<<g15, b128, 0, stream>>>(p, k15, t);
      k_corr15<true><<<g15, b128, 0, stream>>>(t, k15, ap);
      k_reg<0><<<g64, b256, 0, stream>>>(p, rk, rk, rkw, wreg, nullptr, ap,
                                         r, nullptr, nullptr, part);
      if (!last) {
        k_upd_xr<<<dim3(768), b256, 0, stream>>>((float4*)x, (const float4*)p,
                                                 (float4*)r, (const float4*)ap,
                                                 part, part2);
        k_upd_p<<<dim3(768), b256, 0, stream>>>((float4*)p, (const float4*)r,
                                                part, part2);
      } else {
        k_upd_x<<<dim3(768), b256, 0, stream>>>((float4*)x, (const float4*)p, part);
      }
    }
    if (irls == 0)
      k_wupd<<<g64, b256, 0, stream>>>(x, blurred, rk, rtk, rp, wreg);
  }
}

// Round 8
// 1566.804 us; speedup vs baseline: 1.1020x; 1.0556x over previous
//
#include <hip/hip_runtime.h>
#include <math.h>

#define HH 1024
#define WW 1024
#define CHN 3
#define PLANE (HH*WW)
#define IMG (CHN*PLANE)
#define NREG 5
#define EPSV 1e-4f

// ---- workspace layout (in floats) ----
#define OFF_WREG 0
#define OFF_KTWB (5*IMG)
#define OFF_T    (6*IMG)
#define OFF_R    (7*IMG)
#define OFF_P    (8*IMG)
#define OFF_AP   (9*IMG)
#define OFF_PART (10*IMG)          // pAp[2048] | rr[2048] | rr_new[768]

// ---------------------------------------------------------------------------
// init: x = blurred (w_reg needs no init: IRLS-0 uses the W1 path, and k_wupd
// fully overwrites w_reg before IRLS-1 reads it)
__global__ __launch_bounds__(256) void k_init(const float4* __restrict__ b,
                                              float4* __restrict__ x) {
  const int stride = gridDim.x * 256;
  for (int i = blockIdx.x * 256 + threadIdx.x; i < IMG / 4; i += stride)
    x[i] = b[i];
}

// ---------------------------------------------------------------------------
// 15x15 edge-padded correlation. Tile 72 cols x 64 rows, 256 threads,
// each thread 2 rows x 9 cols. Col-group stride 9 -> bank spread <=2-way.
// k15 staged (optionally flipped) into LDS padded 16/row; b128 broadcasts.
template <bool FLIP>
__global__ __launch_bounds__(256) void k_corr15(const float* __restrict__ in,
                                                const float* __restrict__ k15,
                                                float* __restrict__ out) {
  __shared__ float tile[78 * 87];
  __shared__ float kpad[15 * 16];
  const int ch = blockIdx.z;
  const int R0 = blockIdx.y * 64;
  const int C0 = blockIdx.x * 72;
  const int tid = threadIdx.x;
  if (tid < 240) {
    int a = tid >> 4, b = tid & 15;
    float v = 0.f;
    if (b < 15) v = FLIP ? k15[(14 - a) * 15 + (14 - b)] : k15[a * 15 + b];
    kpad[tid] = v;
  }
  const float* inc = in + ch * PLANE;
  for (int i = tid; i < 78 * 86; i += 256) {
    int r = i / 86, c = i - r * 86;
    int gr = min(max(R0 - 7 + r, 0), HH - 1);
    int gc = min(max(C0 - 7 + c, 0), WW - 1);
    tile[r * 87 + c] = inc[gr * WW + gc];
  }
  __syncthreads();
  const int tx = tid & 7, ty = tid >> 3;  // 8 col-groups x 32 row-groups
  const int oi = ty * 2, oj = tx * 9;
  float acc[2][9];
#pragma unroll
  for (int o = 0; o < 2; ++o)
#pragma unroll
    for (int q = 0; q < 9; ++q) acc[o][q] = 0.f;

#pragma unroll 1
  for (int rr = 0; rr < 16; ++rr) {
    float wv[23];
#pragma unroll
    for (int q = 0; q < 23; ++q) wv[q] = tile[(oi + rr) * 87 + oj + q];
#pragma unroll
    for (int o = 0; o < 2; ++o) {
      int a = rr - o;
      if ((unsigned)a < 15u) {
        const float4* kp = (const float4*)&kpad[a * 16];
        float4 kA = kp[0], kB = kp[1], kC = kp[2], kD = kp[3];
        float kv[16] = {kA.x, kA.y, kA.z, kA.w, kB.x, kB.y, kB.z, kB.w,
                        kC.x, kC.y, kC.z, kC.w, kD.x, kD.y, kD.z, kD.w};
#pragma unroll
        for (int b = 0; b < 15; ++b)
#pragma unroll
          for (int q = 0; q < 9; ++q)
            acc[o][q] = fmaf(kv[b], wv[b + q], acc[o][q]);
      }
    }
  }
  float* oc = out + ch * PLANE;
#pragma unroll
  for (int o = 0; o < 2; ++o) {
    const int orow = R0 + oi + o;
#pragma unroll
    for (int q = 0; q < 9; ++q) {
      int gcol = C0 + oj + q;
      if (gcol < WW) oc[orow * WW + gcol] = acc[o][q];
    }
  }
}

// ---------------------------------------------------------------------------
__device__ __forceinline__ void blk_reduce2(float a, float b, float* scratch,
                                            float* o1, float* o2) {
#pragma unroll
  for (int off = 32; off > 0; off >>= 1) {
    a += __shfl_down(a, off, 64);
    b += __shfl_down(b, off, 64);
  }
  __syncthreads();
  const int lane = threadIdx.x & 63, wid = threadIdx.x >> 6;
  if (lane == 0) { scratch[wid] = a; scratch[4 + wid] = b; }
  __syncthreads();
  if (threadIdx.x == 0) {
    *o1 = scratch[0] + scratch[1] + scratch[2] + scratch[3];
    *o2 = scratch[4] + scratch[5] + scratch[6] + scratch[7];
  }
}

// ---------------------------------------------------------------------------
// Pure reg-term kernel: acc = sum_n lam_n * corr5(w_n .* corr5(src,kin_n), flip(rk_n))
// W1=true: w==1 exactly (IRLS iter 0) -> no w_reg global reads.
// MODE 0: ap += acc (ap holds corr15(corr15(p))); partials pAp, rr
// MODE 1: ap += acc
// MODE 2: r = ktwb - ap + acc; p = r   (src=blurred, kin=rtk)
// Tile 64 cols x 32 rows, 256 threads; col-per-lane sliding, conflict-free.
template <int MODE, bool W1>
__global__ __launch_bounds__(256) void k_reg(
    const float* __restrict__ src, const float* __restrict__ kin_all,
    const float* __restrict__ rk, const float* __restrict__ rkw,
    const float* __restrict__ wreg, const float* __restrict__ ktwb,
    float* __restrict__ ap, const float* __restrict__ rin,
    float* __restrict__ rout, float* __restrict__ pout,
    float* __restrict__ part) {
  __shared__ float sbuf[40 * 73];   // src tile: rows R0-4.., cols C0-4..
  __shared__ float vbuf[36 * 69];   // weighted inner-corr: rows R0-2.., cols C0-2..
  __shared__ float kin_s[NREG * 25];
  __shared__ float kf_s[NREG * 25];
  __shared__ float scratch[8];
  const int ch = blockIdx.z;
  const int R0 = blockIdx.y * 32, C0 = blockIdx.x * 64;
  const int tid = threadIdx.x;
  const int lane = tid & 63, wid = tid >> 6;
  const int W = wid * 8;   // 4 waves x 8 output rows

  if (tid < NREG * 25) {
    int n = tid / 25, j = tid - n * 25, a = j / 5, b = j - a * 5;
    kin_s[tid] = kin_all[tid];
    float lw = rkw[n];
    kf_s[tid] = lw * lw * rk[n * 25 + (4 - a) * 5 + (4 - b)];
  }
  const float* sc = src + ch * PLANE;
  for (int i = tid; i < 40 * 72; i += 256) {
    int r = i / 72, c = i - r * 72;
    int gr = min(max(R0 - 4 + r, 0), HH - 1);
    int gc = min(max(C0 - 4 + c, 0), WW - 1);
    sbuf[r * 73 + c] = sc[gr * WW + gc];
  }
  __syncthreads();

  float acc[8];
#pragma unroll
  for (int s = 0; s < 8; ++s) acc[s] = 0.f;

  for (int n = 0; n < NREG; ++n) {
    float kin[25];
#pragma unroll
    for (int j = 0; j < 25; ++j) kin[j] = kin_s[n * 25 + j];
    const float* wn = wreg + (n * CHN + ch) * PLANE;

    // border ring of v (center-clamped = edge replication of inner result)
    // v-region 36x68: main rows 2..33, cols 2..65; ring = 400 entries
    for (int e = tid; e < 400; e += 256) {
      int vr, vc;
      if (e < 136)      { vr = e / 68;            vc = e - (e / 68) * 68; }
      else if (e < 272) { int j2 = e - 136; vr = 34 + j2 / 68; vc = j2 - (j2 / 68) * 68; }
      else              { int j2 = e - 272; vr = 2 + (j2 >> 2);
                          int m = j2 & 3; vc = (m < 2) ? m : 64 + m; }
      int rc = min(max(R0 - 2 + vr, 0), HH - 1);
      int cc = min(max(C0 - 2 + vc, 0), WW - 1);
      int tr = rc - R0 + 4, tc = cc - C0 + 4;
      float s = 0.f;
#pragma unroll
      for (int a = 0; a < 5; ++a)
#pragma unroll
        for (int b = 0; b < 5; ++b)
          s = fmaf(kin[a * 5 + b], sbuf[(tr - 2 + a) * 73 + tc - 2 + b], s);
      vbuf[vr * 69 + vc] = W1 ? s : s * wn[rc * WW + cc];
    }

    // main 64x32 v region: col-per-lane vertical sliding
    float vacc[8];
#pragma unroll
    for (int s = 0; s < 8; ++s) vacc[s] = 0.f;
#pragma unroll
    for (int rr = 0; rr < 12; ++rr) {
      float x5[5];
#pragma unroll
      for (int b = 0; b < 5; ++b) x5[b] = sbuf[(2 + W + rr) * 73 + lane + 2 + b];
#pragma unroll
      for (int a = 0; a < 5; ++a) {
        int s = rr - a;
        if (s >= 0 && s < 8) {
#pragma unroll
          for (int b = 0; b < 5; ++b) vacc[s] = fmaf(kin[a * 5 + b], x5[b], vacc[s]);
        }
      }
    }
    if constexpr (W1) {
#pragma unroll
      for (int s = 0; s < 8; ++s)
        vbuf[(2 + W + s) * 69 + lane + 2] = vacc[s];
    } else {
#pragma unroll
      for (int s = 0; s < 8; ++s)
        vbuf[(2 + W + s) * 69 + lane + 2] = vacc[s] * wn[(R0 + W + s) * WW + C0 + lane];
    }
    __syncthreads();

    float kf[25];
#pragma unroll
    for (int j = 0; j < 25; ++j) kf[j] = kf_s[n * 25 + j];
#pragma unroll
    for (int rv = 0; rv < 12; ++rv) {
      float v5[5];
#pragma unroll
      for (int b = 0; b < 5; ++b) v5[b] = vbuf[(W + rv) * 69 + lane + b];
#pragma unroll
      for (int a = 0; a < 5; ++a) {
        int s = rv - a;
        if (s >= 0 && s < 8) {
#pragma unroll
          for (int b = 0; b < 5; ++b) acc[s] = fmaf(kf[a * 5 + b], v5[b], acc[s]);
        }
      }
    }
    __syncthreads();
  }

  const int obase = ch * PLANE + (R0 + W) * WW + C0 + lane;
  if constexpr (MODE == 2) {
#pragma unroll
    for (int s = 0; s < 8; ++s) {
      float rv = ktwb[obase + s * WW] - ap[obase + s * WW] + acc[s];
      rout[obase + s * WW] = rv;
      pout[obase + s * WW] = rv;
    }
  } else {
    float pap = 0.f, rr2 = 0.f;
#pragma unroll
    for (int s = 0; s < 8; ++s) {
      float av = ap[obase + s * WW] + acc[s];
      ap[obase + s * WW] = av;
      if constexpr (MODE == 0) {
        float pv = src[obase + s * WW];
        float rv = rin[obase + s * WW];
        pap = fmaf(av, pv, pap);
        rr2 = fmaf(rv, rv, rr2);
      }
    }
    if constexpr (MODE == 0) {
      float s1, s2;
      blk_reduce2(pap, rr2, scratch, &s1, &s2);
      if (tid == 0) {
        int bid = (blockIdx.z * 32 + blockIdx.y) * 16 + blockIdx.x;  // < 1536
        part[bid] = s1;
        part[2048 + bid] = s2;
      }
    }
  }
}

// ---------------------------------------------------------------------------
// w_reg update: d_n = corr5(x,rk_n) - corr5(blurred,rtk_n);
// w = pw * (|d|+eps)^(pw-2) via native v_log/v_exp. Col-per-lane, conflict-free.
__global__ __launch_bounds__(256) void k_wupd(
    const float* __restrict__ x, const float* __restrict__ blur,
    const float* __restrict__ rk, const float* __restrict__ rtk,
    const float* __restrict__ rp, float* __restrict__ wreg) {
  __shared__ float xb[68 * 69];
  __shared__ float bb[68 * 69];
  __shared__ float k1s[NREG * 25], k2s[NREG * 25];
  __shared__ float rps[NREG];
  const int ch = blockIdx.z, R0 = blockIdx.y * 64, C0 = blockIdx.x * 64;
  const int tid = threadIdx.x;
  const int lane = tid & 63, wid = tid >> 6, W = wid * 16;
  if (tid < NREG * 25) { k1s[tid] = rk[tid]; k2s[tid] = rtk[tid]; }
  if (tid < NREG) rps[tid] = rp[tid];
  const float* xc = x + ch * PLANE;
  const float* bc = blur + ch * PLANE;
  for (int i = tid; i < 68 * 68; i += 256) {
    int r = i / 68, c = i - r * 68;
    int gr = min(max(R0 - 2 + r, 0), HH - 1);
    int gc = min(max(C0 - 2 + c, 0), WW - 1);
    xb[r * 69 + c] = xc[gr * WW + gc];
    bb[r * 69 + c] = bc[gr * WW + gc];
  }
  __syncthreads();
  for (int n = 0; n < NREG; ++n) {
    float k1[25], k2[25];
#pragma unroll
    for (int j = 0; j < 25; ++j) { k1[j] = k1s[n * 25 + j]; k2[j] = k2s[n * 25 + j]; }
    float d_[16];
#pragma unroll
    for (int s = 0; s < 16; ++s) d_[s] = 0.f;
#pragma unroll
    for (int rr = 0; rr < 20; ++rr) {
      float x5[5], b5[5];
#pragma unroll
      for (int b = 0; b < 5; ++b) {
        x5[b] = xb[(W + rr) * 69 + lane + b];
        b5[b] = bb[(W + rr) * 69 + lane + b];
      }
#pragma unroll
      for (int a = 0; a < 5; ++a) {
        int s = rr - a;
        if (s >= 0 && s < 16) {
#pragma unroll
          for (int b = 0; b < 5; ++b) {
            d_[s] = fmaf(k1[a * 5 + b], x5[b], d_[s]);
            d_[s] = fmaf(-k2[a * 5 + b], b5[b], d_[s]);
          }
        }
      }
    }
    float pw = rps[n];
    float* wc = wreg + (n * CHN + ch) * PLANE + (R0 + W) * WW + C0 + lane;
#pragma unroll
    for (int s = 0; s < 16; ++s) {
      float v = fabsf(d_[s]) + EPSV;
      wc[s * WW] = pw * __expf((pw - 2.f) * __logf(v));
    }
  }
}

// ---------------------------------------------------------------------------
// CG update kernels; each derives its scalar from the partial arrays itself.
__global__ __launch_bounds__(256) void k_upd_xr(
    float4* __restrict__ x, const float4* __restrict__ p,
    float4* __restrict__ r, const float4* __restrict__ ap,
    const float* __restrict__ part, float* __restrict__ part2) {
  __shared__ float scratch[8];
  __shared__ float sAlpha;
  {
    float a = 0.f, b = 0.f;
    for (int i = threadIdx.x; i < 1536; i += 256) {
      a += part[i];           // sum p.Ap
      b += part[2048 + i];    // sum r.r
    }
    float s1, s2;
    blk_reduce2(a, b, scratch, &s1, &s2);
    if (threadIdx.x == 0) sAlpha = s2 / s1;
    __syncthreads();
  }
  const float alpha = sAlpha;
  float s = 0.f;
  const int stride = gridDim.x * 256;
  for (int i = blockIdx.x * 256 + threadIdx.x; i < IMG / 4; i += stride) {
    float4 xv = x[i], pv = p[i], rv = r[i], av = ap[i];
    xv.x += alpha * pv.x; xv.y += alpha * pv.y; xv.z += alpha * pv.z; xv.w += alpha * pv.w;
    rv.x -= alpha * av.x; rv.y -= alpha * av.y; rv.z -= alpha * av.z; rv.w -= alpha * av.w;
    x[i] = xv; r[i] = rv;
    s += rv.x * rv.x + rv.y * rv.y + rv.z * rv.z + rv.w * rv.w;
  }
#pragma unroll
  for (int off = 32; off > 0; off >>= 1) s += __shfl_down(s, off, 64);
  __syncthreads();
  if ((threadIdx.x & 63) == 0) scratch[threadIdx.x >> 6] = s;
  __syncthreads();
  if (threadIdx.x == 0)
    part2[blockIdx.x] = scratch[0] + scratch[1] + scratch[2] + scratch[3];
}

__global__ __launch_bounds__(256) void k_upd_x(
    float4* __restrict__ x, const float4* __restrict__ p,
    const float* __restrict__ part) {
  __shared__ float scratch[8];
  __shared__ float sAlpha;
  {
    float a = 0.f, b = 0.f;
    for (int i = threadIdx.x; i < 1536; i += 256) {
      a += part[i];
      b += part[2048 + i];
    }
    float s1, s2;
    blk_reduce2(a, b, scratch, &s1, &s2);
    if (threadIdx.x == 0) sAlpha = s2 / s1;
    __syncthreads();
  }
  const float alpha = sAlpha;
  const int stride = gridDim.x * 256;
  for (int i = blockIdx.x * 256 + threadIdx.x; i < IMG / 4; i += stride) {
    float4 xv = x[i], pv = p[i];
    xv.x += alpha * pv.x; xv.y += alpha * pv.y; xv.z += alpha * pv.z; xv.w += alpha * pv.w;
    x[i] = xv;
  }
}

__global__ __launch_bounds__(256) void k_upd_p(
    float4* __restrict__ p, const float4* __restrict__ r,
    const float* __restrict__ part, const float* __restrict__ part2) {
  __shared__ float scratch[8];
  __shared__ float sBeta;
  {
    float a = 0.f, b = 0.f;
    for (int i = threadIdx.x; i < 1536; i += 256) {
      if (i < 768) a += part2[i];  // rr_new
      b += part[2048 + i];         // rr_old
    }
    float s1, s2;
    blk_reduce2(a, b, scratch, &s1, &s2);
    if (threadIdx.x == 0) sBeta = s1 / s2;
    __syncthreads();
  }
  const float beta = sBeta;
  const int stride = gridDim.x * 256;
  for (int i = blockIdx.x * 256 + threadIdx.x; i < IMG / 4; i += stride) {
    float4 pv = p[i], rv = r[i];
    pv.x = rv.x + beta * pv.x; pv.y = rv.y + beta * pv.y;
    pv.z = rv.z + beta * pv.z; pv.w = rv.w + beta * pv.w;
    p[i] = pv;
  }
}

// ---------------------------------------------------------------------------
extern "C" void kernel_launch(void* const* d_in, const int* in_sizes, int n_in,
                              void* d_out, int out_size, void* d_ws, size_t ws_size,
                              hipStream_t stream) {
  (void)in_sizes; (void)n_in; (void)out_size; (void)ws_size;
  const float* blurred = (const float*)d_in[0];
  const float* k15 = (const float*)d_in[1];
  const float* rk  = (const float*)d_in[2];
  const float* rkw = (const float*)d_in[3];
  const float* rtk = (const float*)d_in[4];
  const float* rp  = (const float*)d_in[5];

  float* x = (float*)d_out;
  float* ws = (float*)d_ws;
  float* wreg  = ws + OFF_WREG;
  float* ktwb  = ws + OFF_KTWB;
  float* t     = ws + OFF_T;
  float* r     = ws + OFF_R;
  float* p     = ws + OFF_P;
  float* ap    = ws + OFF_AP;
  float* part  = ws + OFF_PART;       // [0..2047] pAp, [2048..4095] rr
  float* part2 = part + 4096;         // [0..767] rr_new

  const dim3 b256(256);
  const dim3 g15(15, 16, CHN);   // corr15 tiles: 72x64
  const dim3 gRG(16, 32, CHN);   // k_reg tiles: 64x32
  const dim3 g64(16, 16, CHN);   // k_wupd tiles: 64x64

  k_init<<<dim3(768), b256, 0, stream>>>((const float4*)blurred, (float4*)x);
  k_corr15<true><<<g15, b256, 0, stream>>>(blurred, k15, ktwb);

  for (int irls = 0; irls < 2; ++irls) {
    // ap = A(x0) = corr15(corr15(x,K),flipK) + reg(x0); then r = rhs - ap; p = r
    k_corr15<false><<<g15, b256, 0, stream>>>(x, k15, t);
    k_corr15<true><<<g15, b256, 0, stream>>>(t, k15, ap);
    if (irls == 0) {
      k_reg<1, true><<<gRG, b256, 0, stream>>>(x, rk, rk, rkw, wreg, nullptr, ap,
                                               nullptr, nullptr, nullptr, nullptr);
      k_reg<2, true><<<gRG, b256, 0, stream>>>(blurred, rtk, rk, rkw, wreg, ktwb, ap,
                                               nullptr, r, p, nullptr);
    } else {
      k_reg<1, false><<<gRG, b256, 0, stream>>>(x, rk, rk, rkw, wreg, nullptr, ap,
                                                nullptr, nullptr, nullptr, nullptr);
      k_reg<2, false><<<gRG, b256, 0, stream>>>(blurred, rtk, rk, rkw, wreg, ktwb, ap,
                                                nullptr, r, p, nullptr);
    }
    for (int cg = 0; cg < 4; ++cg) {
      const bool last = (cg == 3);
      k_corr15<false><<<g15, b256, 0, stream>>>(p, k15, t);
      k_corr15<true><<<g15, b256, 0, stream>>>(t, k15, ap);
      if (irls == 0)
        k_reg<0, true><<<gRG, b256, 0, stream>>>(p, rk, rk, rkw, wreg, nullptr, ap,
                                                 r, nullptr, nullptr, part);
      else
        k_reg<0, false><<<gRG, b256, 0, stream>>>(p, rk, rk, rkw, wreg, nullptr, ap,
                                                  r, nullptr, nullptr, part);
      if (!last) {
        k_upd_xr<<<dim3(768), b256, 0, stream>>>((float4*)x, (const float4*)p,
                                                 (float4*)r, (const float4*)ap,
                                                 part, part2);
        k_upd_p<<<dim3(768), b256, 0, stream>>>((float4*)p, (const float4*)r,
                                                part, part2);
      } else {
        k_upd_x<<<dim3(768), b256, 0, stream>>>((float4*)x, (const float4*)p, part);
      }
    }
    if (irls == 0)
      k_wupd<<<g64, b256, 0, stream>>>(x, blurred, rk, rtk, rp, wreg);
  }
}

// Round 12
// 1438.525 us; speedup vs baseline: 1.2002x; 1.0892x over previous
//
#include <hip/hip_runtime.h>
#include <math.h>

#define HH 1024
#define WW 1024
#define CHN 3
#define PLANE (HH*WW)
#define IMG (CHN*PLANE)
#define NREG 5
#define EPSV 1e-4f

// ---- workspace layout (in floats) ----
#define OFF_WREG 0
#define OFF_KTWB (5*IMG)
#define OFF_T    (6*IMG)
#define OFF_R    (7*IMG)
#define OFF_P    (8*IMG)
#define OFF_AP   (9*IMG)
#define OFF_PART (10*IMG)          // pAp[2048] | rr[2048] | rr_new[768]

// ---------------------------------------------------------------------------
// init: x = blurred (w_reg needs no init: IRLS-0 uses the W1 path, and k_wupd
// fully overwrites w_reg before IRLS-1 reads it)
__global__ __launch_bounds__(256) void k_init(const float4* __restrict__ b,
                                              float4* __restrict__ x) {
  const int stride = gridDim.x * 256;
  for (int i = blockIdx.x * 256 + threadIdx.x; i < IMG / 4; i += stride)
    x[i] = b[i];
}

// ---------------------------------------------------------------------------
// 15x15 edge-padded correlation. Tile 72 cols x 32 rows, 256 threads,
// each thread 1 row x 9 cols (8 col-groups x 32 rows). Grid 1440 blocks.
// Tile stride 88: bank = (24*ty + 9*tx) mod 32 -> <=2-way (free) window reads.
// k15 staged (optionally flipped) into LDS padded 16/row; b128 broadcasts.
template <bool FLIP>
__global__ __launch_bounds__(256) void k_corr15(const float* __restrict__ in,
                                                const float* __restrict__ k15,
                                                float* __restrict__ out) {
  __shared__ float tile[46 * 88];
  __shared__ float kpad[15 * 16];
  const int ch = blockIdx.z;
  const int R0 = blockIdx.y * 32;
  const int C0 = blockIdx.x * 72;
  const int tid = threadIdx.x;
  if (tid < 240) {
    int a = tid >> 4, b = tid & 15;
    float v = 0.f;
    if (b < 15) v = FLIP ? k15[(14 - a) * 15 + (14 - b)] : k15[a * 15 + b];
    kpad[tid] = v;
  }
  const float* inc = in + ch * PLANE;
  for (int i = tid; i < 46 * 86; i += 256) {
    int r = i / 86, c = i - r * 86;
    int gr = min(max(R0 - 7 + r, 0), HH - 1);
    int gc = min(max(C0 - 7 + c, 0), WW - 1);
    tile[r * 88 + c] = inc[gr * WW + gc];
  }
  __syncthreads();
  const int tx = tid & 7, ty = tid >> 3;  // 8 col-groups x 32 rows
  const int oi = ty, oj = tx * 9;
  float acc[9];
#pragma unroll
  for (int q = 0; q < 9; ++q) acc[q] = 0.f;

#pragma unroll 1
  for (int a = 0; a < 15; ++a) {
    float wv[23];
#pragma unroll
    for (int q = 0; q < 23; ++q) wv[q] = tile[(oi + a) * 88 + oj + q];
    const float4* kp = (const float4*)&kpad[a * 16];
    float4 kA = kp[0], kB = kp[1], kC = kp[2], kD = kp[3];
    float kv[16] = {kA.x, kA.y, kA.z, kA.w, kB.x, kB.y, kB.z, kB.w,
                    kC.x, kC.y, kC.z, kC.w, kD.x, kD.y, kD.z, kD.w};
#pragma unroll
    for (int b = 0; b < 15; ++b)
#pragma unroll
      for (int q = 0; q < 9; ++q)
        acc[q] = fmaf(kv[b], wv[b + q], acc[q]);
  }
  float* oc = out + ch * PLANE;
  const int orow = R0 + oi;
#pragma unroll
  for (int q = 0; q < 9; ++q) {
    int gcol = C0 + oj + q;
    if (gcol < WW) oc[orow * WW + gcol] = acc[q];
  }
}

// ---------------------------------------------------------------------------
__device__ __forceinline__ void blk_reduce2(float a, float b, float* scratch,
                                            float* o1, float* o2) {
#pragma unroll
  for (int off = 32; off > 0; off >>= 1) {
    a += __shfl_down(a, off, 64);
    b += __shfl_down(b, off, 64);
  }
  __syncthreads();
  const int lane = threadIdx.x & 63, wid = threadIdx.x >> 6;
  if (lane == 0) { scratch[wid] = a; scratch[4 + wid] = b; }
  __syncthreads();
  if (threadIdx.x == 0) {
    *o1 = scratch[0] + scratch[1] + scratch[2] + scratch[3];
    *o2 = scratch[4] + scratch[5] + scratch[6] + scratch[7];
  }
}

// ---------------------------------------------------------------------------
// Pure reg-term kernel: acc = sum_n lam_n * corr5(w_n .* corr5(src,kin_n), flip(rk_n))
// W1=true: w==1 exactly (IRLS iter 0) -> no w_reg global reads.
// Weighted path prefetches all 5x8 main-region w values into VGPRs at block
// start (40 independent loads, full MLP) so HBM latency hides under compute.
// MODE 0: ap += acc (ap holds corr15(corr15(p))); partials pAp, rr
// MODE 1: ap += acc
// MODE 2: r = ktwb - ap + acc; p = r   (src=blurred, kin=rtk)
// Tile 64 cols x 32 rows, 256 threads; col-per-lane sliding, conflict-free.
template <int MODE, bool W1>
__global__ __launch_bounds__(256) void k_reg(
    const float* __restrict__ src, const float* __restrict__ kin_all,
    const float* __restrict__ rk, const float* __restrict__ rkw,
    const float* __restrict__ wreg, const float* __restrict__ ktwb,
    float* __restrict__ ap, const float* __restrict__ rin,
    float* __restrict__ rout, float* __restrict__ pout,
    float* __restrict__ part) {
  __shared__ float sbuf[40 * 73];   // src tile: rows R0-4.., cols C0-4..
  __shared__ float vbuf[36 * 69];   // weighted inner-corr: rows R0-2.., cols C0-2..
  __shared__ float kin_s[NREG * 25];
  __shared__ float kf_s[NREG * 25];
  __shared__ float scratch[8];
  const int ch = blockIdx.z;
  const int R0 = blockIdx.y * 32, C0 = blockIdx.x * 64;
  const int tid = threadIdx.x;
  const int lane = tid & 63, wid = tid >> 6;
  const int W = wid * 8;   // 4 waves x 8 output rows

  // prefetch main-region w values into registers (weighted path only)
  float wpre[NREG][8];
  if constexpr (!W1) {
#pragma unroll
    for (int n = 0; n < NREG; ++n) {
      const float* wn = wreg + (n * CHN + ch) * PLANE;
#pragma unroll
      for (int s = 0; s < 8; ++s)
        wpre[n][s] = wn[(R0 + W + s) * WW + C0 + lane];
    }
  }

  if (tid < NREG * 25) {
    int n = tid / 25, j = tid - n * 25, a = j / 5, b = j - a * 5;
    kin_s[tid] = kin_all[tid];
    float lw = rkw[n];
    kf_s[tid] = lw * lw * rk[n * 25 + (4 - a) * 5 + (4 - b)];
  }
  const float* sc = src + ch * PLANE;
  for (int i = tid; i < 40 * 72; i += 256) {
    int r = i / 72, c = i - r * 72;
    int gr = min(max(R0 - 4 + r, 0), HH - 1);
    int gc = min(max(C0 - 4 + c, 0), WW - 1);
    sbuf[r * 73 + c] = sc[gr * WW + gc];
  }
  __syncthreads();

  float acc[8];
#pragma unroll
  for (int s = 0; s < 8; ++s) acc[s] = 0.f;

  for (int n = 0; n < NREG; ++n) {
    float kin[25];
#pragma unroll
    for (int j = 0; j < 25; ++j) kin[j] = kin_s[n * 25 + j];
    const float* wn = wreg + (n * CHN + ch) * PLANE;

    // border ring of v (center-clamped = edge replication of inner result)
    // v-region 36x68: main rows 2..33, cols 2..65; ring = 400 entries
    for (int e = tid; e < 400; e += 256) {
      int vr, vc;
      if (e < 136)      { vr = e / 68;            vc = e - (e / 68) * 68; }
      else if (e < 272) { int j2 = e - 136; vr = 34 + j2 / 68; vc = j2 - (j2 / 68) * 68; }
      else              { int j2 = e - 272; vr = 2 + (j2 >> 2);
                          int m = j2 & 3; vc = (m < 2) ? m : 64 + m; }
      int rc = min(max(R0 - 2 + vr, 0), HH - 1);
      int cc = min(max(C0 - 2 + vc, 0), WW - 1);
      int tr = rc - R0 + 4, tc = cc - C0 + 4;
      float s = 0.f;
#pragma unroll
      for (int a = 0; a < 5; ++a)
#pragma unroll
        for (int b = 0; b < 5; ++b)
          s = fmaf(kin[a * 5 + b], sbuf[(tr - 2 + a) * 73 + tc - 2 + b], s);
      vbuf[vr * 69 + vc] = W1 ? s : s * wn[rc * WW + cc];
    }

    // main 64x32 v region: col-per-lane vertical sliding
    float vacc[8];
#pragma unroll
    for (int s = 0; s < 8; ++s) vacc[s] = 0.f;
#pragma unroll
    for (int rr = 0; rr < 12; ++rr) {
      float x5[5];
#pragma unroll
      for (int b = 0; b < 5; ++b) x5[b] = sbuf[(2 + W + rr) * 73 + lane + 2 + b];
#pragma unroll
      for (int a = 0; a < 5; ++a) {
        int s = rr - a;
        if (s >= 0 && s < 8) {
#pragma unroll
          for (int b = 0; b < 5; ++b) vacc[s] = fmaf(kin[a * 5 + b], x5[b], vacc[s]);
        }
      }
    }
    if constexpr (W1) {
#pragma unroll
      for (int s = 0; s < 8; ++s)
        vbuf[(2 + W + s) * 69 + lane + 2] = vacc[s];
    } else {
#pragma unroll
      for (int s = 0; s < 8; ++s)
        vbuf[(2 + W + s) * 69 + lane + 2] = vacc[s] * wpre[n][s];
    }
    __syncthreads();

    float kf[25];
#pragma unroll
    for (int j = 0; j < 25; ++j) kf[j] = kf_s[n * 25 + j];
#pragma unroll
    for (int rv = 0; rv < 12; ++rv) {
      float v5[5];
#pragma unroll
      for (int b = 0; b < 5; ++b) v5[b] = vbuf[(W + rv) * 69 + lane + b];
#pragma unroll
      for (int a = 0; a < 5; ++a) {
        int s = rv - a;
        if (s >= 0 && s < 8) {
#pragma unroll
          for (int b = 0; b < 5; ++b) acc[s] = fmaf(kf[a * 5 + b], v5[b], acc[s]);
        }
      }
    }
    __syncthreads();
  }

  const int obase = ch * PLANE + (R0 + W) * WW + C0 + lane;
  if constexpr (MODE == 2) {
#pragma unroll
    for (int s = 0; s < 8; ++s) {
      float rv = ktwb[obase + s * WW] - ap[obase + s * WW] + acc[s];
      rout[obase + s * WW] = rv;
      pout[obase + s * WW] = rv;
    }
  } else {
    float pap = 0.f, rr2 = 0.f;
#pragma unroll
    for (int s = 0; s < 8; ++s) {
      float av = ap[obase + s * WW] + acc[s];
      ap[obase + s * WW] = av;
      if constexpr (MODE == 0) {
        float pv = src[obase + s * WW];
        float rv = rin[obase + s * WW];
        pap = fmaf(av, pv, pap);
        rr2 = fmaf(rv, rv, rr2);
      }
    }
    if constexpr (MODE == 0) {
      float s1, s2;
      blk_reduce2(pap, rr2, scratch, &s1, &s2);
      if (tid == 0) {
        int bid = (blockIdx.z * 32 + blockIdx.y) * 16 + blockIdx.x;  // < 1536
        part[bid] = s1;
        part[2048 + bid] = s2;
      }
    }
  }
}

// ---------------------------------------------------------------------------
// w_reg update: d_n = corr5(x,rk_n) - corr5(blurred,rtk_n);
// w = pw * (|d|+eps)^(pw-2) via native v_log/v_exp. Tile 64x32 (grid 1536).
__global__ __launch_bounds__(256) void k_wupd(
    const float* __restrict__ x, const float* __restrict__ blur,
    const float* __restrict__ rk, const float* __restrict__ rtk,
    const float* __restrict__ rp, float* __restrict__ wreg) {
  __shared__ float xb[36 * 69];
  __shared__ float bb[36 * 69];
  __shared__ float k1s[NREG * 25], k2s[NREG * 25];
  __shared__ float rps[NREG];
  const int ch = blockIdx.z, R0 = blockIdx.y * 32, C0 = blockIdx.x * 64;
  const int tid = threadIdx.x;
  const int lane = tid & 63, wid = tid >> 6, W = wid * 8;
  if (tid < NREG * 25) { k1s[tid] = rk[tid]; k2s[tid] = rtk[tid]; }
  if (tid < NREG) rps[tid] = rp[tid];
  const float* xc = x + ch * PLANE;
  const float* bc = blur + ch * PLANE;
  for (int i = tid; i < 36 * 68; i += 256) {
    int r = i / 68, c = i - r * 68;
    int gr = min(max(R0 - 2 + r, 0), HH - 1);
    int gc = min(max(C0 - 2 + c, 0), WW - 1);
    xb[r * 69 + c] = xc[gr * WW + gc];
    bb[r * 69 + c] = bc[gr * WW + gc];
  }
  __syncthreads();
  for (int n = 0; n < NREG; ++n) {
    float k1[25], k2[25];
#pragma unroll
    for (int j = 0; j < 25; ++j) { k1[j] = k1s[n * 25 + j]; k2[j] = k2s[n * 25 + j]; }
    float d_[8];
#pragma unroll
    for (int s = 0; s < 8; ++s) d_[s] = 0.f;
#pragma unroll
    for (int rr = 0; rr < 12; ++rr) {
      float x5[5], b5[5];
#pragma unroll
      for (int b = 0; b < 5; ++b) {
        x5[b] = xb[(W + rr) * 69 + lane + b];
        b5[b] = bb[(W + rr) * 69 + lane + b];
      }
#pragma unroll
      for (int a = 0; a < 5; ++a) {
        int s = rr - a;
        if (s >= 0 && s < 8) {
#pragma unroll
          for (int b = 0; b < 5; ++b) {
            d_[s] = fmaf(k1[a * 5 + b], x5[b], d_[s]);
            d_[s] = fmaf(-k2[a * 5 + b], b5[b], d_[s]);
          }
        }
      }
    }
    float pw = rps[n];
    float* wc = wreg + (n * CHN + ch) * PLANE + (R0 + W) * WW + C0 + lane;
#pragma unroll
    for (int s = 0; s < 8; ++s) {
      float v = fabsf(d_[s]) + EPSV;
      wc[s * WW] = pw * __expf((pw - 2.f) * __logf(v));
    }
  }
}

// ---------------------------------------------------------------------------
// CG update kernels; each derives its scalar from the partial arrays itself.
__global__ __launch_bounds__(256) void k_upd_xr(
    float4* __restrict__ x, const float4* __restrict__ p,
    float4* __restrict__ r, const float4* __restrict__ ap,
    const float* __restrict__ part, float* __restrict__ part2) {
  __shared__ float scratch[8];
  __shared__ float sAlpha;
  {
    float a = 0.f, b = 0.f;
    for (int i = threadIdx.x; i < 1536; i += 256) {
      a += part[i];           // sum p.Ap
      b += part[2048 + i];    // sum r.r
    }
    float s1, s2;
    blk_reduce2(a, b, scratch, &s1, &s2);
    if (threadIdx.x == 0) sAlpha = s2 / s1;
    __syncthreads();
  }
  const float alpha = sAlpha;
  float s = 0.f;
  const int stride = gridDim.x * 256;
  for (int i = blockIdx.x * 256 + threadIdx.x; i < IMG / 4; i += stride) {
    float4 xv = x[i], pv = p[i], rv = r[i], av = ap[i];
    xv.x += alpha * pv.x; xv.y += alpha * pv.y; xv.z += alpha * pv.z; xv.w += alpha * pv.w;
    rv.x -= alpha * av.x; rv.y -= alpha * av.y; rv.z -= alpha * av.z; rv.w -= alpha * av.w;
    x[i] = xv; r[i] = rv;
    s += rv.x * rv.x + rv.y * rv.y + rv.z * rv.z + rv.w * rv.w;
  }
#pragma unroll
  for (int off = 32; off > 0; off >>= 1) s += __shfl_down(s, off, 64);
  __syncthreads();
  if ((threadIdx.x & 63) == 0) scratch[threadIdx.x >> 6] = s;
  __syncthreads();
  if (threadIdx.x == 0)
    part2[blockIdx.x] = scratch[0] + scratch[1] + scratch[2] + scratch[3];
}

__global__ __launch_bounds__(256) void k_upd_x(
    float4* __restrict__ x, const float4* __restrict__ p,
    const float* __restrict__ part) {
  __shared__ float scratch[8];
  __shared__ float sAlpha;
  {
    float a = 0.f, b = 0.f;
    for (int i = threadIdx.x; i < 1536; i += 256) {
      a += part[i];
      b += part[2048 + i];
    }
    float s1, s2;
    blk_reduce2(a, b, scratch, &s1, &s2);
    if (threadIdx.x == 0) sAlpha = s2 / s1;
    __syncthreads();
  }
  const float alpha = sAlpha;
  const int stride = gridDim.x * 256;
  for (int i = blockIdx.x * 256 + threadIdx.x; i < IMG / 4; i += stride) {
    float4 xv = x[i], pv = p[i];
    xv.x += alpha * pv.x; xv.y += alpha * pv.y; xv.z += alpha * pv.z; xv.w += alpha * pv.w;
    x[i] = xv;
  }
}

__global__ __launch_bounds__(256) void k_upd_p(
    float4* __restrict__ p, const float4* __restrict__ r,
    const float* __restrict__ part, const float* __restrict__ part2) {
  __shared__ float scratch[8];
  __shared__ float sBeta;
  {
    float a = 0.f, b = 0.f;
    for (int i = threadIdx.x; i < 1536; i += 256) {
      if (i < 768) a += part2[i];  // rr_new
      b += part[2048 + i];         // rr_old
    }
    float s1, s2;
    blk_reduce2(a, b, scratch, &s1, &s2);
    if (threadIdx.x == 0) sBeta = s1 / s2;
    __syncthreads();
  }
  const float beta = sBeta;
  const int stride = gridDim.x * 256;
  for (int i = blockIdx.x * 256 + threadIdx.x; i < IMG / 4; i += stride) {
    float4 pv = p[i], rv = r[i];
    pv.x = rv.x + beta * pv.x; pv.y = rv.y + beta * pv.y;
    pv.z = rv.z + beta * pv.z; pv.w = rv.w + beta * pv.w;
    p[i] = pv;
  }
}

// ---------------------------------------------------------------------------
extern "C" void kernel_launch(void* const* d_in, const int* in_sizes, int n_in,
                              void* d_out, int out_size, void* d_ws, size_t ws_size,
                              hipStream_t stream) {
  (void)in_sizes; (void)n_in; (void)out_size; (void)ws_size;
  const float* blurred = (const float*)d_in[0];
  const float* k15 = (const float*)d_in[1];
  const float* rk  = (const float*)d_in[2];
  const float* rkw = (const float*)d_in[3];
  const float* rtk = (const float*)d_in[4];
  const float* rp  = (const float*)d_in[5];

  float* x = (float*)d_out;
  float* ws = (float*)d_ws;
  float* wreg  = ws + OFF_WREG;
  float* ktwb  = ws + OFF_KTWB;
  float* t     = ws + OFF_T;
  float* r     = ws + OFF_R;
  float* p     = ws + OFF_P;
  float* ap    = ws + OFF_AP;
  float* part  = ws + OFF_PART;       // [0..2047] pAp, [2048..4095] rr
  float* part2 = part + 4096;         // [0..767] rr_new

  const dim3 b256(256);
  const dim3 g15(15, 32, CHN);   // corr15 tiles: 72x32 (1440 blocks)
  const dim3 gRG(16, 32, CHN);   // k_reg tiles: 64x32 (1536 blocks)
  const dim3 gWU(16, 32, CHN);   // k_wupd tiles: 64x32 (1536 blocks)

  k_init<<<dim3(768), b256, 0, stream>>>((const float4*)blurred, (float4*)x);
  k_corr15<true><<<g15, b256, 0, stream>>>(blurred, k15, ktwb);

  for (int irls = 0; irls < 2; ++irls) {
    // ap = A(x0) = corr15(corr15(x,K),flipK) + reg(x0); then r = rhs - ap; p = r
    k_corr15<false><<<g15, b256, 0, stream>>>(x, k15, t);
    k_corr15<true><<<g15, b256, 0, stream>>>(t, k15, ap);
    if (irls == 0) {
      k_reg<1, true><<<gRG, b256, 0, stream>>>(x, rk, rk, rkw, wreg, nullptr, ap,
                                               nullptr, nullptr, nullptr, nullptr);
      k_reg<2, true><<<gRG, b256, 0, stream>>>(blurred, rtk, rk, rkw, wreg, ktwb, ap,
                                               nullptr, r, p, nullptr);
    } else {
      k_reg<1, false><<<gRG, b256, 0, stream>>>(x, rk, rk, rkw, wreg, nullptr, ap,
                                                nullptr, nullptr, nullptr, nullptr);
      k_reg<2, false><<<gRG, b256, 0, stream>>>(blurred, rtk, rk, rkw, wreg, ktwb, ap,
                                                nullptr, r, p, nullptr);
    }
    for (int cg = 0; cg < 4; ++cg) {
      const bool last = (cg == 3);
      k_corr15<false><<<g15, b256, 0, stream>>>(p, k15, t);
      k_corr15<true><<<g15, b256, 0, stream>>>(t, k15, ap);
      if (irls == 0)
        k_reg<0, true><<<gRG, b256, 0, stream>>>(p, rk, rk, rkw, wreg, nullptr, ap,
                                                 r, nullptr, nullptr, part);
      else
        k_reg<0, false><<<gRG, b256, 0, stream>>>(p, rk, rk, rkw, wreg, nullptr, ap,
                                                  r, nullptr, nullptr, part);
      if (!last) {
        k_upd_xr<<<dim3(768), b256, 0, stream>>>((float4*)x, (const float4*)p,
                                                 (float4*)r, (const float4*)ap,
                                                 part, part2);
        k_upd_p<<<dim3(768), b256, 0, stream>>>((float4*)p, (const float4*)r,
                                                part, part2);
      } else {
        k_upd_x<<<dim3(768), b256, 0, stream>>>((float4*)x, (const float4*)p, part);
      }
    }
    if (irls == 0)
      k_wupd<<<gWU, b256, 0, stream>>>(x, blurred, rk, rtk, rp, wreg);
  }
}